// Round 1
// baseline (443.937 us; speedup 1.0000x reference)
//
#include <hip/hip_runtime.h>
#include <hip/hip_bf16.h>

typedef __bf16 bf16x8 __attribute__((ext_vector_type(8)));
typedef float  f32x4  __attribute__((ext_vector_type(4)));

#define N_ROWS 32768
#define D_DIM  256
#define K_PROT 2048

// ws layout (float offsets)
#define WS_Z2    0
#define WS_INVN  32768
#define WS_P2    65536
#define WS_RMIN  67584
#define WS_CMIN  100352

// out layout (float offsets)
#define OUT_X0   0UL
#define OUT_X1   8388608UL
#define OUT_XMAP 16777216UL
#define OUT_CVAE 83886080UL
#define OUT_PROT 83886081UL

// ---------------- K1: per-row norm, copy, normalize, init rowmin ----------------
__global__ __launch_bounds__(256) void k1_rows(
    const float* __restrict__ Z, float* __restrict__ out0, float* __restrict__ out1,
    float* __restrict__ z2, float* __restrict__ invn, unsigned int* __restrict__ rmin)
{
    int row  = (blockIdx.x << 2) + (threadIdx.x >> 6);
    int lane = threadIdx.x & 63;
    size_t base = (size_t)row * D_DIM;
    float4 v = ((const float4*)(Z + base))[lane];
    float ss = v.x*v.x + v.y*v.y + v.z*v.z + v.w*v.w;
    #pragma unroll
    for (int d = 32; d >= 1; d >>= 1) ss += __shfl_xor(ss, d);
    float inv = 1.0f / fmaxf(sqrtf(ss), 1e-12f);
    ((float4*)(out0 + base))[lane] = v;
    float4 xv; xv.x = v.x*inv; xv.y = v.y*inv; xv.z = v.z*inv; xv.w = v.w*inv;
    ((float4*)(out1 + base))[lane] = xv;
    if (lane == 0) { z2[row] = ss; invn[row] = inv; rmin[row] = 0x7f800000u; }
}

// ---------------- K2: prototype squared norms, init colmin ----------------
__global__ __launch_bounds__(256) void k2_prot(
    const float* __restrict__ P, float* __restrict__ p2, unsigned int* __restrict__ cmin)
{
    int row  = (blockIdx.x << 2) + (threadIdx.x >> 6);
    int lane = threadIdx.x & 63;
    float4 v = ((const float4*)(P + (size_t)row * D_DIM))[lane];
    float ss = v.x*v.x + v.y*v.y + v.z*v.z + v.w*v.w;
    #pragma unroll
    for (int d = 32; d >= 1; d >>= 1) ss += __shfl_xor(ss, d);
    if (lane == 0) { p2[row] = ss; cmin[row] = 0x7f800000u; }
}

// ---------------- K3: bf16 MFMA GEMM G = Z * P^T + fused epilogue ----------------
// 128x128 tile, 4 waves (2x2), each wave 64x64 via 4x4 grid of 16x16x32 MFMAs.
#define BM 128
#define BN 128
#define LDSS 40   // bf16 elems per LDS row (32 + 8 pad): 80 B stride, 16B-aligned, 2-way banks (free)

__global__ __launch_bounds__(256, 2) void k3_gemm(
    const float* __restrict__ Z, const float* __restrict__ P,
    const float* __restrict__ z2, const float* __restrict__ p2,
    const float* __restrict__ invn,
    float* __restrict__ xmap,
    unsigned int* __restrict__ rmin, unsigned int* __restrict__ cmin)
{
    __shared__ __bf16 As[BM * LDSS];
    __shared__ __bf16 Bs[BN * LDSS];

    const int tid  = threadIdx.x;
    const int bn   = blockIdx.x & 15;   // 16 n-blocks
    const int bm   = blockIdx.x >> 4;   // 256 m-blocks
    const int lane = tid & 63;
    const int wave = tid >> 6;
    const int wm   = wave >> 1;
    const int wn   = wave & 1;
    const int l15  = lane & 15;
    const int quad = lane >> 4;

    const int m0 = bm * BM;
    const int n0 = bn * BN;

    // staging: 2 threads per row, 16 floats (4 float4) each
    const int srow = tid >> 1;
    const int scol = (tid & 1) << 4;    // 0 or 16

    f32x4 acc[4][4];
    #pragma unroll
    for (int i = 0; i < 4; i++)
        #pragma unroll
        for (int j = 0; j < 4; j++)
            #pragma unroll
            for (int r = 0; r < 4; r++) acc[i][j][r] = 0.0f;

    for (int kt = 0; kt < D_DIM; kt += 32) {
        const float* aSrc = Z + (size_t)(m0 + srow) * D_DIM + kt + scol;
        const float* bSrc = P + (size_t)(n0 + srow) * D_DIM + kt + scol;
        float4 a0 = ((const float4*)aSrc)[0];
        float4 a1 = ((const float4*)aSrc)[1];
        float4 a2 = ((const float4*)aSrc)[2];
        float4 a3 = ((const float4*)aSrc)[3];
        float4 b0 = ((const float4*)bSrc)[0];
        float4 b1 = ((const float4*)bSrc)[1];
        float4 b2 = ((const float4*)bSrc)[2];
        float4 b3 = ((const float4*)bSrc)[3];

        __syncthreads();   // previous iteration's LDS reads complete

        __bf16* aDst = As + srow * LDSS + scol;
        __bf16* bDst = Bs + srow * LDSS + scol;
        {
            bf16x8 w;
            w[0]=(__bf16)a0.x; w[1]=(__bf16)a0.y; w[2]=(__bf16)a0.z; w[3]=(__bf16)a0.w;
            w[4]=(__bf16)a1.x; w[5]=(__bf16)a1.y; w[6]=(__bf16)a1.z; w[7]=(__bf16)a1.w;
            *(bf16x8*)aDst = w;
            w[0]=(__bf16)a2.x; w[1]=(__bf16)a2.y; w[2]=(__bf16)a2.z; w[3]=(__bf16)a2.w;
            w[4]=(__bf16)a3.x; w[5]=(__bf16)a3.y; w[6]=(__bf16)a3.z; w[7]=(__bf16)a3.w;
            *(bf16x8*)(aDst + 8) = w;
            w[0]=(__bf16)b0.x; w[1]=(__bf16)b0.y; w[2]=(__bf16)b0.z; w[3]=(__bf16)b0.w;
            w[4]=(__bf16)b1.x; w[5]=(__bf16)b1.y; w[6]=(__bf16)b1.z; w[7]=(__bf16)b1.w;
            *(bf16x8*)bDst = w;
            w[0]=(__bf16)b2.x; w[1]=(__bf16)b2.y; w[2]=(__bf16)b2.z; w[3]=(__bf16)b2.w;
            w[4]=(__bf16)b3.x; w[5]=(__bf16)b3.y; w[6]=(__bf16)b3.z; w[7]=(__bf16)b3.w;
            *(bf16x8*)(bDst + 8) = w;
        }
        __syncthreads();

        bf16x8 af[4], bf[4];
        #pragma unroll
        for (int i = 0; i < 4; i++)
            af[i] = *(const bf16x8*)(As + (wm*64 + i*16 + l15) * LDSS + quad*8);
        #pragma unroll
        for (int j = 0; j < 4; j++)
            bf[j] = *(const bf16x8*)(Bs + (wn*64 + j*16 + l15) * LDSS + quad*8);
        #pragma unroll
        for (int i = 0; i < 4; i++)
            #pragma unroll
            for (int j = 0; j < 4; j++)
                acc[i][j] = __builtin_amdgcn_mfma_f32_16x16x32_bf16(af[i], bf[j], acc[i][j], 0, 0, 0);
    }

    // ---- epilogue ----
    // C/D layout (m89-verified): col(n) = lane&15, row(m) = quad*4 + reg
    float invr[16], zzr[16];
    #pragma unroll
    for (int i = 0; i < 4; i++)
        #pragma unroll
        for (int r = 0; r < 4; r++) {
            int gm = m0 + wm*64 + i*16 + quad*4 + r;
            invr[i*4+r] = invn[gm];
            zzr[i*4+r]  = z2[gm];
        }
    float pp[4];
    #pragma unroll
    for (int j = 0; j < 4; j++) pp[j] = p2[n0 + wn*64 + j*16 + l15];

    float cminv[4] = {3.0e38f, 3.0e38f, 3.0e38f, 3.0e38f};

    #pragma unroll
    for (int i = 0; i < 4; i++) {
        #pragma unroll
        for (int r = 0; r < 4; r++) {
            int gm = m0 + wm*64 + i*16 + quad*4 + r;
            float zi = zzr[i*4+r], iv = invr[i*4+r];
            size_t orow = (size_t)gm * K_PROT + n0 + wn*64 + l15;
            float rv = 3.0e38f;
            #pragma unroll
            for (int j = 0; j < 4; j++) {
                float g = acc[i][j][r];
                xmap[orow + j*16] = g * iv;
                float d = sqrtf(fmaxf(zi + pp[j] - 2.0f*g, 0.0f));
                rv = fminf(rv, d);
                cminv[j] = fminf(cminv[j], d);
            }
            #pragma unroll
            for (int s = 1; s < 16; s <<= 1) rv = fminf(rv, __shfl_xor(rv, s));
            if (l15 == 0) atomicMin(&rmin[gm], __float_as_uint(rv));
        }
    }
    #pragma unroll
    for (int j = 0; j < 4; j++) {
        float cv = cminv[j];
        cv = fminf(cv, __shfl_xor(cv, 16));
        cv = fminf(cv, __shfl_xor(cv, 32));
        if (quad == 0) atomicMin(&cmin[n0 + wn*64 + j*16 + l15], __float_as_uint(cv));
    }
}

// ---------------- K4: final reductions + scalar losses ----------------
__global__ __launch_bounds__(1024) void k4_final(
    const float* __restrict__ rminf, const float* __restrict__ cminf,
    const float* __restrict__ recon, const float* __restrict__ kl,
    const float* __restrict__ mmd, float* __restrict__ out)
{
    __shared__ float sr[16], sc[16];
    int tid = threadIdx.x;
    float a = 0.0f, b = 0.0f;
    for (int i = tid; i < N_ROWS; i += 1024) a += rminf[i];
    for (int i = tid; i < K_PROT; i += 1024) b += cminf[i];
    #pragma unroll
    for (int d = 32; d >= 1; d >>= 1) { a += __shfl_xor(a, d); b += __shfl_xor(b, d); }
    int w = tid >> 6, lane = tid & 63;
    if (lane == 0) { sr[w] = a; sc[w] = b; }
    __syncthreads();
    if (tid == 0) {
        float SA = 0.0f, SB = 0.0f;
        #pragma unroll
        for (int i = 0; i < 16; i++) { SA += sr[i]; SB += sc[i]; }
        out[OUT_CVAE] = recon[0] + 0.5f*kl[0] + mmd[0];
        out[OUT_PROT] = 0.5f*(SA / (float)N_ROWS) + 0.5f*(SB / (float)K_PROT);
    }
}

extern "C" void kernel_launch(void* const* d_in, const int* in_sizes, int n_in,
                              void* d_out, int out_size, void* d_ws, size_t ws_size,
                              hipStream_t stream)
{
    const float* Z     = (const float*)d_in[0];
    const float* P     = (const float*)d_in[1];
    const float* recon = (const float*)d_in[2];
    const float* kl    = (const float*)d_in[3];
    const float* mmd   = (const float*)d_in[4];
    float* out = (float*)d_out;
    float* ws  = (float*)d_ws;

    float* z2   = ws + WS_Z2;
    float* invn = ws + WS_INVN;
    float* p2   = ws + WS_P2;
    unsigned int* rmin = (unsigned int*)(ws + WS_RMIN);
    unsigned int* cmin = (unsigned int*)(ws + WS_CMIN);

    hipLaunchKernelGGL(k1_rows, dim3(N_ROWS/4), dim3(256), 0, stream,
                       Z, out + OUT_X0, out + OUT_X1, z2, invn, rmin);
    hipLaunchKernelGGL(k2_prot, dim3(K_PROT/4), dim3(256), 0, stream, P, p2, cmin);
    hipLaunchKernelGGL(k3_gemm, dim3((N_ROWS/BM)*(K_PROT/BN)), dim3(256), 0, stream,
                       Z, P, z2, p2, invn, out + OUT_XMAP, rmin, cmin);
    hipLaunchKernelGGL(k4_final, dim3(1), dim3(1024), 0, stream,
                       (const float*)rmin, (const float*)cmin, recon, kl, mmd, out);
}

// Round 3
// 427.766 us; speedup vs baseline: 1.0378x; 1.0378x over previous
//
#include <hip/hip_runtime.h>
#include <hip/hip_bf16.h>

typedef __bf16 bf16x8 __attribute__((ext_vector_type(8)));
typedef __bf16 bf16x4 __attribute__((ext_vector_type(4)));
typedef float  f32x4  __attribute__((ext_vector_type(4)));

#define N_ROWS 32768
#define D_DIM  256
#define K_PROT 2048

// ws layout (float offsets)
#define WS_Z2    0
#define WS_INVN  32768
#define WS_P2    65536
#define WS_RMIN  67584
#define WS_CMIN  100352
#define WS_ZB    102400   // bf16 Z copy: 32768*256 bf16 = 16 MB (byte off 409600, 16B-aligned)
#define WS_PB    (102400 + 4194304)  // bf16 P copy: 2048*256 bf16 = 1 MB

// out layout (float offsets)
#define OUT_X0   0UL
#define OUT_X1   8388608UL
#define OUT_XMAP 16777216UL
#define OUT_CVAE 83886080UL
#define OUT_PROT 83886081UL

__device__ __forceinline__ void gload16(const __bf16* gsrc, const __bf16* ldst) {
    auto g = (const __attribute__((address_space(1))) unsigned int*)(unsigned long long)gsrc;
    auto l = (__attribute__((address_space(3))) unsigned int*)(unsigned long long)ldst;
    __builtin_amdgcn_global_load_lds(g, l, 16, 0, 0);
}

// ---------------- K1: per-row norm, copy, normalize, bf16 cast, init rowmin ----------------
__global__ __launch_bounds__(256) void k1_rows(
    const float* __restrict__ Z, float* __restrict__ out0, float* __restrict__ out1,
    float* __restrict__ z2, float* __restrict__ invn, unsigned int* __restrict__ rmin,
    __bf16* __restrict__ Zb)
{
    int row  = (blockIdx.x << 2) + (threadIdx.x >> 6);
    int lane = threadIdx.x & 63;
    size_t base = (size_t)row * D_DIM;
    float4 v = ((const float4*)(Z + base))[lane];
    float ss = v.x*v.x + v.y*v.y + v.z*v.z + v.w*v.w;
    #pragma unroll
    for (int d = 32; d >= 1; d >>= 1) ss += __shfl_xor(ss, d);
    float inv = 1.0f / fmaxf(sqrtf(ss), 1e-12f);
    ((float4*)(out0 + base))[lane] = v;
    float4 xv; xv.x = v.x*inv; xv.y = v.y*inv; xv.z = v.z*inv; xv.w = v.w*inv;
    ((float4*)(out1 + base))[lane] = xv;
    bf16x4 bv; bv[0]=(__bf16)v.x; bv[1]=(__bf16)v.y; bv[2]=(__bf16)v.z; bv[3]=(__bf16)v.w;
    ((bf16x4*)(Zb + base))[lane] = bv;
    if (lane == 0) { z2[row] = ss; invn[row] = inv; rmin[row] = 0x7f800000u; }
}

// ---------------- K2: prototype squared norms, bf16 cast, init colmin ----------------
__global__ __launch_bounds__(256) void k2_prot(
    const float* __restrict__ P, float* __restrict__ p2, unsigned int* __restrict__ cmin,
    __bf16* __restrict__ Pb)
{
    int row  = (blockIdx.x << 2) + (threadIdx.x >> 6);
    int lane = threadIdx.x & 63;
    size_t base = (size_t)row * D_DIM;
    float4 v = ((const float4*)(P + base))[lane];
    float ss = v.x*v.x + v.y*v.y + v.z*v.z + v.w*v.w;
    #pragma unroll
    for (int d = 32; d >= 1; d >>= 1) ss += __shfl_xor(ss, d);
    bf16x4 bv; bv[0]=(__bf16)v.x; bv[1]=(__bf16)v.y; bv[2]=(__bf16)v.z; bv[3]=(__bf16)v.w;
    ((bf16x4*)(Pb + base))[lane] = bv;
    if (lane == 0) { p2[row] = ss; cmin[row] = 0x7f800000u; }
}

// ---------------- K3: bf16 MFMA GEMM G = Zb * Pb^T + fused epilogue ----------------
// m97 structure: 128x128 tile, BK=64, global_load_lds width-16 staging, no LDS pad.
#define BM 128
#define BN 128
#define BK 64

__global__ __launch_bounds__(256, 2) void k3_gemm(
    const __bf16* __restrict__ Zb, const __bf16* __restrict__ Pb,
    const float* __restrict__ z2, const float* __restrict__ p2,
    const float* __restrict__ invn,
    float* __restrict__ xmap,
    unsigned int* __restrict__ rmin, unsigned int* __restrict__ cmin)
{
    __shared__ __bf16 As[BM * BK];   // 16 KB, rows of 128 B, contiguous
    __shared__ __bf16 Bs[BN * BK];   // 16 KB

    const int tid  = threadIdx.x;
    const int bn   = blockIdx.x & 15;   // 16 n-blocks
    const int bm   = blockIdx.x >> 4;   // 256 m-blocks
    const int lane = tid & 63;
    const int wave = tid >> 6;
    const int wm   = wave >> 1;
    const int wn   = wave & 1;
    const int l15  = lane & 15;
    const int quad = lane >> 4;

    const int m0 = bm * BM;
    const int n0 = bn * BN;

    f32x4 acc[4][4];
    #pragma unroll
    for (int i = 0; i < 4; i++)
        #pragma unroll
        for (int j = 0; j < 4; j++)
            #pragma unroll
            for (int r = 0; r < 4; r++) acc[i][j][r] = 0.0f;

    // staging: chunk = (it*4+wave)*64 + lane (16B units).
    // global src: row = chunk>>3, colchunk = chunk&7 (= lane&7).
    // LDS dst elem offset = chunk*8 -> wave-uniform base (it*4+wave)*512, lane adds lane*16B.
    const int ch_row[4] = {
        ((0*4 + wave)*64 + lane) >> 3, ((1*4 + wave)*64 + lane) >> 3,
        ((2*4 + wave)*64 + lane) >> 3, ((3*4 + wave)*64 + lane) >> 3 };
    const int ch_c = lane & 7;

    for (int kt = 0; kt < D_DIM; kt += BK) {
        #pragma unroll
        for (int it = 0; it < 4; it++) {
            const __bf16* aS = Zb + (size_t)(m0 + ch_row[it]) * D_DIM + kt + ch_c * 8;
            const __bf16* bS = Pb + (size_t)(n0 + ch_row[it]) * D_DIM + kt + ch_c * 8;
            gload16(aS, As + (it*4 + wave) * 512);
            gload16(bS, Bs + (it*4 + wave) * 512);
        }
        __syncthreads();   // drains vmcnt(0): staging visible

        #pragma unroll
        for (int s = 0; s < 2; s++) {
            bf16x8 af[4], bfr[4];
            #pragma unroll
            for (int i = 0; i < 4; i++)
                af[i] = *(const bf16x8*)(As + (wm*64 + i*16 + l15) * BK + s*32 + quad*8);
            #pragma unroll
            for (int j = 0; j < 4; j++)
                bfr[j] = *(const bf16x8*)(Bs + (wn*64 + j*16 + l15) * BK + s*32 + quad*8);
            #pragma unroll
            for (int i = 0; i < 4; i++)
                #pragma unroll
                for (int j = 0; j < 4; j++)
                    acc[i][j] = __builtin_amdgcn_mfma_f32_16x16x32_bf16(af[i], bfr[j], acc[i][j], 0, 0, 0);
        }
        __syncthreads();   // protect LDS before next stage
    }

    // ---- epilogue ----
    // C/D layout (m89-verified): col(n) = lane&15, row(m) = quad*4 + reg
    float invr[16], zzr[16];
    #pragma unroll
    for (int i = 0; i < 4; i++)
        #pragma unroll
        for (int r = 0; r < 4; r++) {
            int gm = m0 + wm*64 + i*16 + quad*4 + r;
            invr[i*4+r] = invn[gm];
            zzr[i*4+r]  = z2[gm];
        }
    float pp[4];
    #pragma unroll
    for (int j = 0; j < 4; j++) pp[j] = p2[n0 + wn*64 + j*16 + l15];

    float cminv[4] = {3.0e38f, 3.0e38f, 3.0e38f, 3.0e38f};

    #pragma unroll
    for (int i = 0; i < 4; i++) {
        #pragma unroll
        for (int r = 0; r < 4; r++) {
            int gm = m0 + wm*64 + i*16 + quad*4 + r;
            float zi = zzr[i*4+r], iv = invr[i*4+r];
            size_t orow = (size_t)gm * K_PROT + n0 + wn*64 + l15;
            float rv = 3.0e38f;
            #pragma unroll
            for (int j = 0; j < 4; j++) {
                float g = acc[i][j][r];
                xmap[orow + j*16] = g * iv;
                float d = sqrtf(fmaxf(zi + pp[j] - 2.0f*g, 0.0f));
                rv = fminf(rv, d);
                cminv[j] = fminf(cminv[j], d);
            }
            #pragma unroll
            for (int s = 1; s < 16; s <<= 1) rv = fminf(rv, __shfl_xor(rv, s));
            if (l15 == 0) atomicMin(&rmin[gm], __float_as_uint(rv));
        }
    }
    #pragma unroll
    for (int j = 0; j < 4; j++) {
        float cv = cminv[j];
        cv = fminf(cv, __shfl_xor(cv, 16));
        cv = fminf(cv, __shfl_xor(cv, 32));
        if (quad == 0) atomicMin(&cmin[n0 + wn*64 + j*16 + l15], __float_as_uint(cv));
    }
}

// ---------------- K4: final reductions + scalar losses ----------------
__global__ __launch_bounds__(1024) void k4_final(
    const float* __restrict__ rminf, const float* __restrict__ cminf,
    const float* __restrict__ recon, const float* __restrict__ kl,
    const float* __restrict__ mmd, float* __restrict__ out)
{
    __shared__ float sr[16], sc[16];
    int tid = threadIdx.x;
    float a = 0.0f, b = 0.0f;
    for (int i = tid; i < N_ROWS; i += 1024) a += rminf[i];
    for (int i = tid; i < K_PROT; i += 1024) b += cminf[i];
    #pragma unroll
    for (int d = 32; d >= 1; d >>= 1) { a += __shfl_xor(a, d); b += __shfl_xor(b, d); }
    int w = tid >> 6, lane = tid & 63;
    if (lane == 0) { sr[w] = a; sc[w] = b; }
    __syncthreads();
    if (tid == 0) {
        float SA = 0.0f, SB = 0.0f;
        #pragma unroll
        for (int i = 0; i < 16; i++) { SA += sr[i]; SB += sc[i]; }
        out[OUT_CVAE] = recon[0] + 0.5f*kl[0] + mmd[0];
        out[OUT_PROT] = 0.5f*(SA / (float)N_ROWS) + 0.5f*(SB / (float)K_PROT);
    }
}

extern "C" void kernel_launch(void* const* d_in, const int* in_sizes, int n_in,
                              void* d_out, int out_size, void* d_ws, size_t ws_size,
                              hipStream_t stream)
{
    const float* Z     = (const float*)d_in[0];
    const float* P     = (const float*)d_in[1];
    const float* recon = (const float*)d_in[2];
    const float* kl    = (const float*)d_in[3];
    const float* mmd   = (const float*)d_in[4];
    float* out = (float*)d_out;
    float* ws  = (float*)d_ws;

    float* z2   = ws + WS_Z2;
    float* invn = ws + WS_INVN;
    float* p2   = ws + WS_P2;
    unsigned int* rmin = (unsigned int*)(ws + WS_RMIN);
    unsigned int* cmin = (unsigned int*)(ws + WS_CMIN);
    __bf16* Zb = (__bf16*)(ws + WS_ZB);
    __bf16* Pb = (__bf16*)(ws + WS_PB);

    hipLaunchKernelGGL(k1_rows, dim3(N_ROWS/4), dim3(256), 0, stream,
                       Z, out + OUT_X0, out + OUT_X1, z2, invn, rmin, Zb);
    hipLaunchKernelGGL(k2_prot, dim3(K_PROT/4), dim3(256), 0, stream, P, p2, cmin, Pb);
    hipLaunchKernelGGL(k3_gemm, dim3((N_ROWS/BM)*(K_PROT/BN)), dim3(256), 0, stream,
                       Zb, Pb, z2, p2, invn, out + OUT_XMAP, rmin, cmin);
    hipLaunchKernelGGL(k4_final, dim3(1), dim3(1024), 0, stream,
                       (const float*)rmin, (const float*)cmin, recon, kl, mmd, out);
}